// Round 5
// baseline (308.637 us; speedup 1.0000x reference)
//
#include <hip/hip_runtime.h>
#include <hip/hip_bf16.h>
#include <stdint.h>

typedef __bf16 bf16_t;
typedef __bf16 bf16x8 __attribute__((ext_vector_type(8)));
typedef float f32x4 __attribute__((ext_vector_type(4)));

#define B_  8
#define S_  1024
#define D_  1024
#define H_  16
#define DH_ 64

static __device__ __forceinline__ f32x4 mfma_bf16(bf16x8 a, bf16x8 b, f32x4 c) {
  return __builtin_amdgcn_mfma_f32_16x16x32_bf16(a, b, c, 0, 0, 0);
}

// async global->LDS, 16 bytes per lane; LDS dest = wave-uniform base + lane*16
#define GLOAD_LDS16(g, l)                                                     \
  __builtin_amdgcn_global_load_lds(                                           \
      (const __attribute__((address_space(1))) void*)(g),                     \
      (__attribute__((address_space(3))) void*)(l), 16, 0, 0)

// ---------------------------------------------------------------------------
// Transpose four 1024x1024 f32 weights -> bf16 transposed: Wt[n][k] = W[k][n]
// grid (16,16,4), block 256
// ---------------------------------------------------------------------------
__global__ __launch_bounds__(256) void transpose4(
    const float* __restrict__ w0, const float* __restrict__ w1,
    const float* __restrict__ w2, const float* __restrict__ w3,
    bf16_t* __restrict__ t0, bf16_t* __restrict__ t1,
    bf16_t* __restrict__ t2, bf16_t* __restrict__ t3)
{
  __shared__ float tile[64][65];
  const float* src; bf16_t* dst;
  switch (blockIdx.z) {
    case 0: src = w0; dst = t0; break;
    case 1: src = w1; dst = t1; break;
    case 2: src = w2; dst = t2; break;
    default: src = w3; dst = t3; break;
  }
  const int tx = threadIdx.x & 63;
  const int ty = threadIdx.x >> 6;
  const int c0 = blockIdx.x * 64, r0 = blockIdx.y * 64;
#pragma unroll
  for (int r = ty; r < 64; r += 4)
    tile[r][tx] = src[(size_t)(r0 + r) * 1024 + c0 + tx];
  __syncthreads();
#pragma unroll
  for (int r = ty; r < 64; r += 4)
    dst[(size_t)(c0 + r) * 1024 + r0 + tx] = (bf16_t)tile[tx][r];
}

// ---------------------------------------------------------------------------
// Convert Q/K/V f32 -> bf16 (contiguous). grid (4096,3), block 256, 8 elem/thr.
// ---------------------------------------------------------------------------
__global__ __launch_bounds__(256) void convert_qkv(
    const float* __restrict__ q, const float* __restrict__ k,
    const float* __restrict__ v,
    bf16_t* __restrict__ qo, bf16_t* __restrict__ ko, bf16_t* __restrict__ vo)
{
  const float* src; bf16_t* dst;
  switch (blockIdx.y) {
    case 0: src = q; dst = qo; break;
    case 1: src = k; dst = ko; break;
    default: src = v; dst = vo; break;
  }
  const size_t i = ((size_t)blockIdx.x * 256 + threadIdx.x) * 8;
  float4 a = *(const float4*)(src + i);
  float4 b = *(const float4*)(src + i + 4);
  bf16x8 o;
  o[0] = (bf16_t)a.x; o[1] = (bf16_t)a.y; o[2] = (bf16_t)a.z; o[3] = (bf16_t)a.w;
  o[4] = (bf16_t)b.x; o[5] = (bf16_t)b.y; o[6] = (bf16_t)b.z; o[7] = (bf16_t)b.w;
  *(bf16x8*)(dst + i) = o;
}

// ---------------------------------------------------------------------------
// Transpose V: [B,H,S,64] -> [B,H,64,S].  grid (16, 128): x=s-tile, y=b*H+h.
// ---------------------------------------------------------------------------
__global__ __launch_bounds__(256) void transposeV(
    const bf16_t* __restrict__ src, bf16_t* __restrict__ dst)
{
  __shared__ bf16_t t[64 * 72];     // row stride 72 elems (144B, 16B-aligned)
  const size_t base = (size_t)blockIdx.y * (64 * 1024);
  const int s0 = blockIdx.x * 64;
#pragma unroll
  for (int it = 0; it < 2; ++it) {
    const int c = it * 256 + threadIdx.x;
    const int r = c >> 3, col8 = (c & 7) * 8;
    bf16x8 v = *(const bf16x8*)(src + base + (size_t)(s0 + r) * 64 + col8);
    *(bf16x8*)(t + r * 72 + col8) = v;
  }
  __syncthreads();
#pragma unroll
  for (int it = 0; it < 2; ++it) {
    const int c = it * 256 + threadIdx.x;
    const int d = c >> 3, sc8 = (c & 7) * 8;
    bf16x8 v;
#pragma unroll
    for (int j = 0; j < 8; ++j) v[j] = t[(sc8 + j) * 72 + d];
    *(bf16x8*)(dst + base + (size_t)d * 1024 + s0 + sc8) = v;
  }
}

// ---------------------------------------------------------------------------
// GEMM core, R4 fix: LDS-traffic-minimal geometry (the measured bottleneck).
//   BM=BN=256, BK=64; 512 thr = 8 waves (2M x 4N), per-wave output 128x64
//   (M_rep=8, N_rep=4): LDS traffic 30.5 KB/MFLOP vs 42 for 64x64 waves.
//   Per K-tile per wave: 8 B-frag reads (held for whole tile) + 2x8 A-frag
//   reads (two 32-MFMA halves) = 24 ds_read_b128; 64 MFMA.
//   2-buffer LDS (128 KB): stage tile t+2 into buf[t&1] AFTER barrier#1
//   (all reads of tile t done); vmcnt(8) keeps the staged tile's 8 loads in
//   flight across the iteration (~3000 cy of latency cover); 2 barriers/iter.
//   XOR slot-swizzle via inverse-swizzled global source (rule #21) - same
//   proven map as R2/R4 (0 bank conflicts measured).
//   Projections M-FUSED: A = [Qc;Kc;Vc] = [24576,1024] (contiguous in ws),
//   seg = tileM>>5 selects weight + output segment (also contiguous).
// MODE: 0 = C f32 row-major [8192,1024]; 1 = C bf16 scatter into [B,H,S,64].
// ---------------------------------------------------------------------------
#define BM_G 256
#define BN_G 256
#define BK_G 64
#define KDIM 1024
#define NK_G (KDIM / BK_G)                  // 16
#define TILE_EL (BM_G * BK_G)               // 16384 elems = 32 KB per operand
#define LDS_BYTES (2 * 2 * TILE_EL * 2)     // 2 buf x (A+B) x 32KB = 131072 B

template <int MODE>
__device__ __forceinline__ void gemm_core(
    const bf16_t* __restrict__ Ap,   // fused [Mtot][1024]; rows via tileM
    const bf16_t* __restrict__ Bp,   // per-seg Bt [>=256*(tileN+1)][1024]
    void* __restrict__ Cp,           // per-seg C base
    bf16_t* smem, int tileM, int tileMloc, int tileN)
{
  bf16_t* const As = smem;                   // 2 x TILE_EL
  bf16_t* const Bs = smem + 2 * TILE_EL;     // 2 x TILE_EL

  const int tid  = threadIdx.x;
  const int wv   = tid >> 6;
  const int lane = tid & 63;
  const int wm   = wv >> 2;                  // 0..1 (M position, 128 rows)
  const int wn   = wv & 3;                   // 0..3 (N position, 64 cols)
  const int quad = lane >> 4;
  const int l15  = lane & 15;

  // staging: one gload line = 512 thr x 16B = 8KB = 64 rows x 128B.
  // lane -> row lr = lane>>3 within wave's 8-row slice, 16B-slot lane&7.
  // Inverse swizzle on global side: slot s holds global slot s^(row&7).
  const int lr  = lane >> 3;
  const int swz = (((lane & 7) ^ lr) << 3);
  const bf16_t* gA0 = Ap + (size_t)(tileM * BM_G + wv * 8 + lr) * KDIM + swz;
  const bf16_t* gB0 = Bp + (size_t)(tileN * BN_G + wv * 8 + lr) * KDIM + swz;
  const int lOff = wv * 512;                 // wave slice within a 4096-el line

  // 8 gloads stage one K-tile (A 4 lines + B 4 lines, 64 rows each)
#define STAGE8(koff, buf) do {                                                  \
    GLOAD_LDS16(gA0 + (koff),                       As + (buf)*TILE_EL + 0*4096 + lOff); \
    GLOAD_LDS16(gA0 + (size_t)64  * KDIM + (koff),  As + (buf)*TILE_EL + 1*4096 + lOff); \
    GLOAD_LDS16(gA0 + (size_t)128 * KDIM + (koff),  As + (buf)*TILE_EL + 2*4096 + lOff); \
    GLOAD_LDS16(gA0 + (size_t)192 * KDIM + (koff),  As + (buf)*TILE_EL + 3*4096 + lOff); \
    GLOAD_LDS16(gB0 + (koff),                       Bs + (buf)*TILE_EL + 0*4096 + lOff); \
    GLOAD_LDS16(gB0 + (size_t)64  * KDIM + (koff),  Bs + (buf)*TILE_EL + 1*4096 + lOff); \
    GLOAD_LDS16(gB0 + (size_t)128 * KDIM + (koff),  Bs + (buf)*TILE_EL + 2*4096 + lOff); \
    GLOAD_LDS16(gB0 + (size_t)192 * KDIM + (koff),  Bs + (buf)*TILE_EL + 3*4096 + lOff); \
  } while (0)

  f32x4 acc[8][4];
#pragma unroll
  for (int mi = 0; mi < 8; ++mi)
#pragma unroll
    for (int ni = 0; ni < 4; ++ni)
      acc[mi][ni] = (f32x4){0.f, 0.f, 0.f, 0.f};

  // prologue: tiles 0,1 -> bufs 0,1 (16 loads); wait tile 0 (8 stay in flight)
  STAGE8(0, 0);
  STAGE8(BK_G, 1);
  asm volatile("s_waitcnt vmcnt(8)" ::: "memory");
  __builtin_amdgcn_s_barrier();

  for (int t = 0; t < NK_G; ++t) {
    const int cb = (t & 1) * TILE_EL;

    bf16x8 bfr[2][4], af[2][4];
    // B frags: read once, live for the whole K-tile
#pragma unroll
    for (int kk = 0; kk < 2; ++kk) {
      const int sl = (((quad + (kk << 2)) ^ (l15 & 7)) << 3);
#pragma unroll
      for (int ni = 0; ni < 4; ++ni)
        bfr[kk][ni] = *(const bf16x8*)(Bs + cb + (wn * 64 + ni * 16 + l15) * BK_G + sl);
    }
    // A half 0 (rows wm*128 + 0..63)
#pragma unroll
    for (int kk = 0; kk < 2; ++kk) {
      const int sl = (((quad + (kk << 2)) ^ (l15 & 7)) << 3);
#pragma unroll
      for (int mi = 0; mi < 4; ++mi)
        af[kk][mi] = *(const bf16x8*)(As + cb + (wm * 128 + mi * 16 + l15) * BK_G + sl);
    }
    asm volatile("s_waitcnt lgkmcnt(0)" ::: "memory");
    __builtin_amdgcn_sched_barrier(0);
    __builtin_amdgcn_s_setprio(1);
#pragma unroll
    for (int kk = 0; kk < 2; ++kk)
#pragma unroll
      for (int mi = 0; mi < 4; ++mi)
#pragma unroll
        for (int ni = 0; ni < 4; ++ni)
          acc[mi][ni] = mfma_bf16(af[kk][mi], bfr[kk][ni], acc[mi][ni]);
    __builtin_amdgcn_s_setprio(0);
    // A half 1 (rows wm*128 + 64..127); WAR on af handled by reg dependency
#pragma unroll
    for (int kk = 0; kk < 2; ++kk) {
      const int sl = (((quad + (kk << 2)) ^ (l15 & 7)) << 3);
#pragma unroll
      for (int mi = 0; mi < 4; ++mi)
        af[kk][mi] = *(const bf16x8*)(As + cb + (wm * 128 + 64 + mi * 16 + l15) * BK_G + sl);
    }
    asm volatile("s_waitcnt lgkmcnt(0)" ::: "memory");
    __builtin_amdgcn_sched_barrier(0);
    __builtin_amdgcn_s_setprio(1);
#pragma unroll
    for (int kk = 0; kk < 2; ++kk)
#pragma unroll
      for (int mi = 0; mi < 4; ++mi)
#pragma unroll
        for (int ni = 0; ni < 4; ++ni)
          acc[4 + mi][ni] = mfma_bf16(af[kk][mi], bfr[kk][ni], acc[4 + mi][ni]);
    __builtin_amdgcn_s_setprio(0);

    asm volatile("" ::: "memory");
    __builtin_amdgcn_s_barrier();            // all waves done reading buf[t&1]

    if (t < NK_G - 2) {
      STAGE8((size_t)(t + 2) * BK_G, t & 1); // overwrite just-consumed buf
      // retire tile t+1's 8 loads; t+2's 8 stay in flight a full iteration
      asm volatile("s_waitcnt vmcnt(8)" ::: "memory");
    } else if (t == NK_G - 2) {
      asm volatile("s_waitcnt vmcnt(0)" ::: "memory"); // t+1 issued 1 iter ago
    }
    if (t < NK_G - 1) {
      asm volatile("" ::: "memory");
      __builtin_amdgcn_s_barrier();          // next tile fully landed for all
    }
  }
#undef STAGE8

  // epilogue: C/D frag layout col=l15(N), row=quad*4+r(M)
#pragma unroll
  for (int mi = 0; mi < 8; ++mi) {
#pragma unroll
    for (int ni = 0; ni < 4; ++ni) {
#pragma unroll
      for (int r = 0; r < 4; ++r) {
        const int row = tileMloc * BM_G + wm * 128 + mi * 16 + quad * 4 + r;
        const int col = tileN * BN_G + wn * 64 + ni * 16 + l15;
        if (MODE == 0) {
          ((float*)Cp)[(size_t)row * 1024 + col] = acc[mi][ni][r];
        } else {
          const int b = row >> 10, s = row & 1023;
          const int h = col >> 6,  d = col & 63;
          ((bf16_t*)Cp)[(((size_t)(b * H_ + h) << 10) | s) * DH_ + d] =
              (bf16_t)acc[mi][ni][r];
        }
      }
    }
  }
}

// Fused projection GEMM: A=[Qc;Kc;Vc] (24576x1024), seg = tileM>>5 selects
// weight (WqT/WkT/WvT contiguous) and output (Qb/Kb/Vb contiguous).
// grid (384,1,1), block 512, 128KB dyn LDS. XCD owns contiguous M-slab.
__global__ __launch_bounds__(512, 2) void gemm_proj(
    const bf16_t* __restrict__ A, const bf16_t* __restrict__ Bw,
    bf16_t* __restrict__ Cb)
{
  extern __shared__ bf16_t smem[];
  const int xcd = blockIdx.x & 7;
  const int r   = blockIdx.x >> 3;           // 0..47
  const int tileN = r & 3;                   // N fastest -> same-M co-resident
  const int tileM = xcd * 12 + (r >> 2);     // 0..95
  const int seg = tileM >> 5;                // 0..2
  gemm_core<1>(A, Bw + ((size_t)seg << 20), (void*)(Cb + ((size_t)seg << 23)),
               smem, tileM, tileM & 31, tileN);
}

// Output GEMM: f32 row-major C. grid (128,1,1), block 512, 128KB dyn LDS.
__global__ __launch_bounds__(512, 2) void gemm_out(
    const bf16_t* __restrict__ Ap, const bf16_t* __restrict__ Bp,
    float* __restrict__ Cp)
{
  extern __shared__ bf16_t smem[];
  const int xcd = blockIdx.x & 7;
  const int r   = blockIdx.x >> 3;           // 0..15
  const int tileN = r & 3;
  const int tileM = xcd * 4 + (r >> 2);      // 0..31
  gemm_core<0>(Ap, Bp, (void*)Cp, smem, tileM, tileM, tileN);
}

// ---------------------------------------------------------------------------
// Flash attention v4: m97-shaped block-cooperative K-loop. (unchanged)
// ---------------------------------------------------------------------------
__global__ __launch_bounds__(256) void attn64(
    const bf16_t* __restrict__ Q,
    const bf16_t* __restrict__ Kv,
    const bf16_t* __restrict__ Vt,
    const int* __restrict__ valid_lens,
    bf16_t* __restrict__ O)
{
  const int h  = blockIdx.x;
  const int qt = blockIdx.y;
  const int b  = blockIdx.z;
  const int tid  = threadIdx.x;
  const int wave = tid >> 6;
  const int lane = tid & 63;
  const int quad = lane >> 4;
  const int l15  = lane & 15;

  const int L   = valid_lens[b];
  const int nkt = (L + 63) >> 6;

  const size_t base = ((size_t)(b * H_ + h)) * S_ * DH_;
  const bf16_t* Qp = Q  + base;
  const bf16_t* Kp = Kv + base;
  const bf16_t* Vp = Vt + base;     // [64][1024] per (b,h)

  __shared__ bf16_t KsA[64 * 32];   // K tile, d 0..31   [key][d]
  __shared__ bf16_t KsB[64 * 32];   // K tile, d 32..63
  __shared__ bf16_t VsA[64 * 32];   // V^T tile, keys 0..31  [d][key]
  __shared__ bf16_t VsB[64 * 32];   // V^T tile, keys 32..63
  __shared__ bf16_t Pb[4][16 * 72]; // per-wave P [q][key]
  bf16_t* const Pw = &Pb[wave][0];

  const int sr = tid >> 2;
  const int sj = (tid & 3) << 3;
  const int ldsOff = (wave * 64) * 8;      // wave-uniform LDS base offset

  const int qrow = qt * 64 + wave * 16 + l15;
  const bf16x8 qf0 = *(const bf16x8*)(Qp + (size_t)qrow * DH_ + quad * 8);
  const bf16x8 qf1 = *(const bf16x8*)(Qp + (size_t)qrow * DH_ + 32 + quad * 8);

  f32x4 o[4];
  float lsum[4];
#pragma unroll
  for (int r = 0; r < 4; ++r) {
    o[r] = (f32x4){0.f, 0.f, 0.f, 0.f};
    lsum[r] = 0.f;
  }

  for (int kt = 0; kt < nkt; ++kt) {
    const int k0 = kt * 64;

    __syncthreads();   // prior tile's LDS reads complete
    GLOAD_LDS16(Kp + (size_t)(k0 + sr) * DH_ + sj,      KsA + ldsOff);
    GLOAD_LDS16(Kp + (size_t)(k0 + sr) * DH_ + 32 + sj, KsB + ldsOff);
    GLOAD_LDS16(Vp + (size_t)sr * S_ + k0 + sj,         VsA + ldsOff);
    GLOAD_LDS16(Vp + (size_t)sr * S_ + k0 + 32 + sj,    VsB + ldsOff);
    __syncthreads();   // staging drained

    // ---- scores: S = Q K^T ----
    f32x4 sc[4];
#pragma unroll
    for (int n16 = 0; n16 < 4; ++n16) {
      const int row = (n16 * 16 + l15) * 32 + quad * 8;
      bf16x8 kf0 = *(const bf16x8*)(KsA + row);
      bf16x8 kf1 = *(const bf16x8*)(KsB + row);
      f32x4 s = (f32x4){0.f, 0.f, 0.f, 0.f};
      s = mfma_bf16(qf0, kf0, s);
      s = mfma_bf16(qf1, kf1, s);
      sc[n16] = s;
    }

    // ---- p = exp(s/8), mask tail tile ----
    if (k0 + 64 <= L) {
#pragma unroll
      for (int n16 = 0; n16 < 4; ++n16) {
#pragma unroll
        for (int r = 0; r < 4; ++r) {
          const float p = __expf(sc[n16][r] * 0.125f);
          lsum[r] += p;
          Pw[(quad * 4 + r) * 72 + n16 * 16 + l15] = (bf16_t)p;
        }
      }
    } else {
#pragma unroll
      for (int n16 = 0; n16 < 4; ++n16) {
        const bool valid = (k0 + n16 * 16 + l15) < L;
#pragma unroll
        for (int r = 0; r < 4; ++r) {
          const float p = valid ? __expf(sc[n16][r] * 0.125f) : 0.f;
          lsum[r] += p;
          Pw[(quad * 4 + r) * 72 + n16 * 16 + l15] = (bf16_t)p;
        }
      }
    }

    // ---- O += P @ V ----
    const bf16x8 pf0 = *(const bf16x8*)(Pw + l15 * 72 + quad * 8);
    const bf16x8 pf1 = *(const bf16x8*)(Pw + l15 * 72 + 32 + quad * 8);
#pragma unroll
    for (int dt = 0; dt < 4; ++dt) {
      const int row = (dt * 16 + l15) * 32 + quad * 8;
      bf16x8 vf0 = *(const bf16x8*)(VsA + row);
      bf16x8 vf1 = *(const bf16x8*)(VsB + row);
      o[dt] = mfma_bf16(pf0, vf0, o[dt]);
      o[dt] = mfma_bf16(pf1, vf1, o[dt]);
    }
  }

  // ---- row-sum reduce, normalize, write [B,S,H*64] ----
  float inv[4];
#pragma unroll
  for (int r = 0; r < 4; ++r) {
    float t = lsum[r];
    t += __shfl_xor(t, 1, 64);
    t += __shfl_xor(t, 2, 64);
    t += __shfl_xor(t, 4, 64);
    t += __shfl_xor(t, 8, 64);
    inv[r] = 1.f / t;
  }
  const int qout = qt * 64 + wave * 16 + quad * 4;
#pragma unroll
  for (int dt = 0; dt < 4; ++dt) {
#pragma unroll
    for (int r = 0; r < 4; ++r) {
      const float v = o[dt][r] * inv[r];
      O[((size_t)(b * S_ + qout + r)) * (H_ * DH_) + h * DH_ + dt * 16 + l15] = (bf16_t)v;
    }
  }
}

// ---------------------------------------------------------------------------
extern "C" void kernel_launch(void* const* d_in, const int* in_sizes, int n_in,
                              void* d_out, int out_size, void* d_ws, size_t ws_size,
                              hipStream_t stream) {
  const float* queries = (const float*)d_in[0];
  const float* keys    = (const float*)d_in[1];
  const float* values  = (const float*)d_in[2];
  const float* Wq      = (const float*)d_in[3];
  const float* Wk      = (const float*)d_in[4];
  const float* Wv      = (const float*)d_in[5];
  const float* Wo      = (const float*)d_in[6];
  const int* valid_lens = (const int*)d_in[7];
  float* out = (float*)d_out;

  bf16_t* ws = (bf16_t*)d_ws;
  const size_t MB = 1024 * 1024;     // elements (bf16)
  bf16_t* WqT = ws + 0 * MB;         // WqT,WkT,WvT contiguous (seg<<20)
  bf16_t* WkT = ws + 1 * MB;
  bf16_t* WvT = ws + 2 * MB;
  bf16_t* WoT = ws + 3 * MB;
  bf16_t* Qc  = ws + 4 * MB;         // Qc,Kc,Vc contiguous -> fused A 24576x1024
  bf16_t* Kc  = ws + 12 * MB;
  bf16_t* Vc  = ws + 20 * MB;
  bf16_t* Qb  = ws + 28 * MB;        // Qb,Kb,Vb contiguous (seg<<23)
  bf16_t* Kb  = ws + 36 * MB;
  bf16_t* Vb  = ws + 44 * MB;
  bf16_t* VbT = ws + 52 * MB;        // [B,H,64,S] transposed V
  bf16_t* Ab  = ws + 60 * MB;        // [B,S,1024] attn out  (total 136 MB)

  // allow 128 KB dynamic LDS for the pipelined GEMMs (host API, capture-safe)
  (void)hipFuncSetAttribute((const void*)gemm_proj,
                            hipFuncAttributeMaxDynamicSharedMemorySize, LDS_BYTES);
  (void)hipFuncSetAttribute((const void*)gemm_out,
                            hipFuncAttributeMaxDynamicSharedMemorySize, LDS_BYTES);

  transpose4<<<dim3(16, 16, 4), 256, 0, stream>>>(Wq, Wk, Wv, Wo, WqT, WkT, WvT, WoT);

  convert_qkv<<<dim3(4096, 3), 256, 0, stream>>>(queries, keys, values, Qc, Kc, Vc);

  gemm_proj<<<dim3(384, 1, 1), 512, LDS_BYTES, stream>>>(Qc, WqT, Qb);

  transposeV<<<dim3(16, 128), 256, 0, stream>>>(Vb, VbT);

  attn64<<<dim3(16, 16, 8), 256, 0, stream>>>(Qb, Kb, VbT, valid_lens, Ab);

  gemm_out<<<dim3(128, 1, 1), 512, LDS_BYTES, stream>>>(Ab, WoT, out);
}

// Round 6
// 284.537 us; speedup vs baseline: 1.0847x; 1.0847x over previous
//
#include <hip/hip_runtime.h>
#include <hip/hip_bf16.h>
#include <stdint.h>

typedef __bf16 bf16_t;
typedef __bf16 bf16x8 __attribute__((ext_vector_type(8)));
typedef float f32x4 __attribute__((ext_vector_type(4)));

#define B_  8
#define S_  1024
#define D_  1024
#define H_  16
#define DH_ 64

static __device__ __forceinline__ f32x4 mfma_bf16(bf16x8 a, bf16x8 b, f32x4 c) {
  return __builtin_amdgcn_mfma_f32_16x16x32_bf16(a, b, c, 0, 0, 0);
}

// async global->LDS, 16 bytes per lane; LDS dest = wave-uniform base + lane*16
#define GLOAD_LDS16(g, l)                                                     \
  __builtin_amdgcn_global_load_lds(                                           \
      (const __attribute__((address_space(1))) void*)(g),                     \
      (__attribute__((address_space(3))) void*)(l), 16, 0, 0)

// ---------------------------------------------------------------------------
// Transpose four 1024x1024 f32 weights -> bf16 transposed: Wt[n][k] = W[k][n]
// grid (16,16,4), block 256
// ---------------------------------------------------------------------------
__global__ __launch_bounds__(256) void transpose4(
    const float* __restrict__ w0, const float* __restrict__ w1,
    const float* __restrict__ w2, const float* __restrict__ w3,
    bf16_t* __restrict__ t0, bf16_t* __restrict__ t1,
    bf16_t* __restrict__ t2, bf16_t* __restrict__ t3)
{
  __shared__ float tile[64][65];
  const float* src; bf16_t* dst;
  switch (blockIdx.z) {
    case 0: src = w0; dst = t0; break;
    case 1: src = w1; dst = t1; break;
    case 2: src = w2; dst = t2; break;
    default: src = w3; dst = t3; break;
  }
  const int tx = threadIdx.x & 63;
  const int ty = threadIdx.x >> 6;
  const int c0 = blockIdx.x * 64, r0 = blockIdx.y * 64;
#pragma unroll
  for (int r = ty; r < 64; r += 4)
    tile[r][tx] = src[(size_t)(r0 + r) * 1024 + c0 + tx];
  __syncthreads();
#pragma unroll
  for (int r = ty; r < 64; r += 4)
    dst[(size_t)(c0 + r) * 1024 + r0 + tx] = (bf16_t)tile[tx][r];
}

// ---------------------------------------------------------------------------
// Convert Q/K/V f32 -> bf16 (contiguous). grid (4096,3), block 256, 8 elem/thr.
// ---------------------------------------------------------------------------
__global__ __launch_bounds__(256) void convert_qkv(
    const float* __restrict__ q, const float* __restrict__ k,
    const float* __restrict__ v,
    bf16_t* __restrict__ qo, bf16_t* __restrict__ ko, bf16_t* __restrict__ vo)
{
  const float* src; bf16_t* dst;
  switch (blockIdx.y) {
    case 0: src = q; dst = qo; break;
    case 1: src = k; dst = ko; break;
    default: src = v; dst = vo; break;
  }
  const size_t i = ((size_t)blockIdx.x * 256 + threadIdx.x) * 8;
  float4 a = *(const float4*)(src + i);
  float4 b = *(const float4*)(src + i + 4);
  bf16x8 o;
  o[0] = (bf16_t)a.x; o[1] = (bf16_t)a.y; o[2] = (bf16_t)a.z; o[3] = (bf16_t)a.w;
  o[4] = (bf16_t)b.x; o[5] = (bf16_t)b.y; o[6] = (bf16_t)b.z; o[7] = (bf16_t)b.w;
  *(bf16x8*)(dst + i) = o;
}

// ---------------------------------------------------------------------------
// Transpose V: [B,H,S,64] -> [B,H,64,S].  grid (16, 128): x=s-tile, y=b*H+h.
// ---------------------------------------------------------------------------
__global__ __launch_bounds__(256) void transposeV(
    const bf16_t* __restrict__ src, bf16_t* __restrict__ dst)
{
  __shared__ bf16_t t[64 * 72];     // row stride 72 elems (144B, 16B-aligned)
  const size_t base = (size_t)blockIdx.y * (64 * 1024);
  const int s0 = blockIdx.x * 64;
#pragma unroll
  for (int it = 0; it < 2; ++it) {
    const int c = it * 256 + threadIdx.x;
    const int r = c >> 3, col8 = (c & 7) * 8;
    bf16x8 v = *(const bf16x8*)(src + base + (size_t)(s0 + r) * 64 + col8);
    *(bf16x8*)(t + r * 72 + col8) = v;
  }
  __syncthreads();
#pragma unroll
  for (int it = 0; it < 2; ++it) {
    const int c = it * 256 + threadIdx.x;
    const int d = c >> 3, sc8 = (c & 7) * 8;
    bf16x8 v;
#pragma unroll
    for (int j = 0; j < 8; ++j) v[j] = t[(sc8 + j) * 72 + d];
    *(bf16x8*)(dst + base + (size_t)d * 1024 + s0 + sc8) = v;
  }
}

// ---------------------------------------------------------------------------
// GEMM core, R5 fix: CO-RESIDENCY geometry. All 1-block/CU schedules (R2-R5)
// pinned at MfmaUtil 27-29%: barrier-locked waves make the CU ALTERNATE
// LDS-read burst <-> MFMA burst (sum, not max). Fix = 2 blocks/CU so one
// block's MFMAs fill the other's read/stage/barrier stalls (m97/m114
// implicit overlap — the one proven mechanism not yet combined with our
// 0-conflict + counted-vmcnt core).
//   BM=256, BN=128, BK=32; 512 thr = 8 waves (4M x 2N), 64x64 out per wave
//   (acc 4x4 = 64 VGPR; __launch_bounds__(512,4) caps VGPR at 128 ->
//   16 waves/CU = 2 blocks co-resident; LDS 48 KB dbuf -> fits 2x).
//   Per K-tile: 8 ds_read_b128 + 16 MFMA per wave; 3 gload_lds; 2 barriers;
//   counted vmcnt(3) (never 0 mid-loop).
//   Swizzle (64B rows): LDS slot' = (slot + row>>1)&3, applied INVERSE on
//   the global source (rule #21); frag reads use the same map -> 2-way
//   aliasing = free. gload dest stays linear.
//   XCD: xcd owns contiguous M-slab; N varies fastest (same-M co-resident).
// MODE: 0 = C f32 row-major; 1 = C bf16 scatter into [B,H,S,64].
// ---------------------------------------------------------------------------
#define BM_G 256
#define BN_G 128
#define BK_G 32
#define KDIM 1024
#define NK_G (KDIM / BK_G)                  // 32
#define AEL (BM_G * BK_G)                   // 8192 elems = 16 KB
#define BEL (BN_G * BK_G)                   // 4096 elems = 8 KB
#define LDS_BYTES ((2 * (AEL + BEL)) * 2)   // 49152 B

template <int MODE>
__device__ __forceinline__ void gemm_core(
    const bf16_t* __restrict__ Ap,   // fused [Mtot][1024]; rows via tileM
    const bf16_t* __restrict__ Bp,   // per-seg Bt
    void* __restrict__ Cp,           // per-seg C base
    bf16_t* smem, int tileM, int tileMloc, int tileN)
{
  bf16_t* const As = smem;                   // 2 x AEL
  bf16_t* const Bs = smem + 2 * AEL;         // 2 x BEL

  const int tid  = threadIdx.x;
  const int wv   = tid >> 6;
  const int lane = tid & 63;
  const int wm   = wv >> 1;                  // 0..3 (M, 64 rows)
  const int wn   = wv & 1;                   // 0..1 (N, 64 cols)
  const int quad = lane >> 4;
  const int l15  = lane & 15;

  // staging: one gload line = 512 thr x 16B = 8KB = 128 rows x 64B.
  // lane -> row wv*16 + (lane>>2), LDS slot lane&3.
  // Inverse swizzle on global side: LDS slot s' holds global slot
  // (s' - row>>1)&3.  (row+128 keeps the same value: 64 ≡ 0 mod 4.)
  const int srow = wv * 16 + (lane >> 2);
  const int sg   = (((lane & 3) - (srow >> 1)) & 3) << 3;   // elems
  const bf16_t* gA = Ap + (size_t)(tileM * BM_G + srow) * KDIM + sg;
  const bf16_t* gB = Bp + (size_t)(tileN * BN_G + srow) * KDIM + sg;
  const int lw = wv * 512;                   // wave slice (elems) in a line

#define STAGE3(koff, buf) do {                                                \
    GLOAD_LDS16(gA + (koff),                     As + (buf) * AEL + lw);      \
    GLOAD_LDS16(gA + (size_t)128 * KDIM + (koff), As + (buf) * AEL + 4096 + lw); \
    GLOAD_LDS16(gB + (koff),                     Bs + (buf) * BEL + lw);      \
  } while (0)

  f32x4 acc[4][4];
#pragma unroll
  for (int mi = 0; mi < 4; ++mi)
#pragma unroll
    for (int ni = 0; ni < 4; ++ni)
      acc[mi][ni] = (f32x4){0.f, 0.f, 0.f, 0.f};

  // prologue: tiles 0,1 -> bufs 0,1; wait tile 0 (tile 1's 3 stay in flight)
  STAGE3(0, 0);
  STAGE3(BK_G, 1);
  asm volatile("s_waitcnt vmcnt(3)" ::: "memory");
  __builtin_amdgcn_s_barrier();

  for (int t = 0; t < NK_G; ++t) {
    const int cbA = (t & 1) * AEL;
    const int cbB = (t & 1) * BEL;

    bf16x8 af[4], bfr[4];
#pragma unroll
    for (int mi = 0; mi < 4; ++mi) {
      const int row = wm * 64 + mi * 16 + l15;
      af[mi] = *(const bf16x8*)(As + cbA + row * BK_G + (((quad + (row >> 1)) & 3) << 3));
    }
#pragma unroll
    for (int ni = 0; ni < 4; ++ni) {
      const int row = wn * 64 + ni * 16 + l15;
      bfr[ni] = *(const bf16x8*)(Bs + cbB + row * BK_G + (((quad + (row >> 1)) & 3) << 3));
    }
    asm volatile("s_waitcnt lgkmcnt(0)" ::: "memory");
    __builtin_amdgcn_sched_barrier(0);
    __builtin_amdgcn_s_setprio(1);
#pragma unroll
    for (int mi = 0; mi < 4; ++mi)
#pragma unroll
      for (int ni = 0; ni < 4; ++ni)
        acc[mi][ni] = mfma_bf16(af[mi], bfr[ni], acc[mi][ni]);
    __builtin_amdgcn_s_setprio(0);
    __builtin_amdgcn_sched_barrier(0);
    asm volatile("" ::: "memory");
    __builtin_amdgcn_s_barrier();            // all waves done reading buf t&1

    if (t + 2 < NK_G) {
      STAGE3((size_t)(t + 2) * BK_G, t & 1); // overwrite just-consumed buf
      asm volatile("s_waitcnt vmcnt(3)" ::: "memory");  // tile t+1 landed
    } else if (t + 2 == NK_G) {
      asm volatile("s_waitcnt vmcnt(0)" ::: "memory");  // last tile landed
    }
    if (t + 1 < NK_G) {
      asm volatile("" ::: "memory");
      __builtin_amdgcn_s_barrier();
    }
  }
#undef STAGE3

  // epilogue: C/D frag layout col=l15(N), row=quad*4+r(M)
#pragma unroll
  for (int mi = 0; mi < 4; ++mi) {
#pragma unroll
    for (int ni = 0; ni < 4; ++ni) {
#pragma unroll
      for (int r = 0; r < 4; ++r) {
        const int row = tileMloc * BM_G + wm * 64 + mi * 16 + quad * 4 + r;
        const int col = tileN * BN_G + wn * 64 + ni * 16 + l15;
        if (MODE == 0) {
          ((float*)Cp)[(size_t)row * 1024 + col] = acc[mi][ni][r];
        } else {
          const int b = row >> 10, s = row & 1023;
          const int h = col >> 6,  d = col & 63;
          ((bf16_t*)Cp)[(((size_t)(b * H_ + h) << 10) | s) * DH_ + d] =
              (bf16_t)acc[mi][ni][r];
        }
      }
    }
  }
}

// Fused projection GEMM: A=[Qc;Kc;Vc] (24576x1024), seg = tileM>>5 selects
// weight (WqT/WkT/WvT contiguous) + output (Qb/Kb/Vb contiguous).
// grid (768,1,1), block 512, 48KB dyn LDS, 2 blocks/CU.
__global__ __launch_bounds__(512, 4) void gemm_proj(
    const bf16_t* __restrict__ A, const bf16_t* __restrict__ Bw,
    bf16_t* __restrict__ Cb)
{
  extern __shared__ bf16_t smem[];
  const int xcd = blockIdx.x & 7;
  const int r   = blockIdx.x >> 3;           // 0..95
  const int tileN = r & 7;                   // N fastest -> same-M co-resident
  const int tileM = xcd * 12 + (r >> 3);     // 0..95
  const int seg = tileM >> 5;                // 0..2
  gemm_core<1>(A, Bw + ((size_t)seg << 20), (void*)(Cb + ((size_t)seg << 23)),
               smem, tileM, tileM & 31, tileN);
}

// Output GEMM: f32 row-major C. grid (256,1,1), block 512, 48KB dyn LDS.
__global__ __launch_bounds__(512, 4) void gemm_out(
    const bf16_t* __restrict__ Ap, const bf16_t* __restrict__ Bp,
    float* __restrict__ Cp)
{
  extern __shared__ bf16_t smem[];
  const int xcd = blockIdx.x & 7;
  const int r   = blockIdx.x >> 3;           // 0..31
  const int tileN = r & 7;
  const int tileM = xcd * 4 + (r >> 3);      // 0..31
  gemm_core<0>(Ap, Bp, (void*)Cp, smem, tileM, tileM, tileN);
}

// ---------------------------------------------------------------------------
// Flash attention v4: m97-shaped block-cooperative K-loop. (unchanged)
// ---------------------------------------------------------------------------
__global__ __launch_bounds__(256) void attn64(
    const bf16_t* __restrict__ Q,
    const bf16_t* __restrict__ Kv,
    const bf16_t* __restrict__ Vt,
    const int* __restrict__ valid_lens,
    bf16_t* __restrict__ O)
{
  const int h  = blockIdx.x;
  const int qt = blockIdx.y;
  const int b  = blockIdx.z;
  const int tid  = threadIdx.x;
  const int wave = tid >> 6;
  const int lane = tid & 63;
  const int quad = lane >> 4;
  const int l15  = lane & 15;

  const int L   = valid_lens[b];
  const int nkt = (L + 63) >> 6;

  const size_t base = ((size_t)(b * H_ + h)) * S_ * DH_;
  const bf16_t* Qp = Q  + base;
  const bf16_t* Kp = Kv + base;
  const bf16_t* Vp = Vt + base;     // [64][1024] per (b,h)

  __shared__ bf16_t KsA[64 * 32];   // K tile, d 0..31   [key][d]
  __shared__ bf16_t KsB[64 * 32];   // K tile, d 32..63
  __shared__ bf16_t VsA[64 * 32];   // V^T tile, keys 0..31  [d][key]
  __shared__ bf16_t VsB[64 * 32];   // V^T tile, keys 32..63
  __shared__ bf16_t Pb[4][16 * 72]; // per-wave P [q][key]
  bf16_t* const Pw = &Pb[wave][0];

  const int sr = tid >> 2;
  const int sj = (tid & 3) << 3;
  const int ldsOff = (wave * 64) * 8;      // wave-uniform LDS base offset

  const int qrow = qt * 64 + wave * 16 + l15;
  const bf16x8 qf0 = *(const bf16x8*)(Qp + (size_t)qrow * DH_ + quad * 8);
  const bf16x8 qf1 = *(const bf16x8*)(Qp + (size_t)qrow * DH_ + 32 + quad * 8);

  f32x4 o[4];
  float lsum[4];
#pragma unroll
  for (int r = 0; r < 4; ++r) {
    o[r] = (f32x4){0.f, 0.f, 0.f, 0.f};
    lsum[r] = 0.f;
  }

  for (int kt = 0; kt < nkt; ++kt) {
    const int k0 = kt * 64;

    __syncthreads();   // prior tile's LDS reads complete
    GLOAD_LDS16(Kp + (size_t)(k0 + sr) * DH_ + sj,      KsA + ldsOff);
    GLOAD_LDS16(Kp + (size_t)(k0 + sr) * DH_ + 32 + sj, KsB + ldsOff);
    GLOAD_LDS16(Vp + (size_t)sr * S_ + k0 + sj,         VsA + ldsOff);
    GLOAD_LDS16(Vp + (size_t)sr * S_ + k0 + 32 + sj,    VsB + ldsOff);
    __syncthreads();   // staging drained

    // ---- scores: S = Q K^T ----
    f32x4 sc[4];
#pragma unroll
    for (int n16 = 0; n16 < 4; ++n16) {
      const int row = (n16 * 16 + l15) * 32 + quad * 8;
      bf16x8 kf0 = *(const bf16x8*)(KsA + row);
      bf16x8 kf1 = *(const bf16x8*)(KsB + row);
      f32x4 s = (f32x4){0.f, 0.f, 0.f, 0.f};
      s = mfma_bf16(qf0, kf0, s);
      s = mfma_bf16(qf1, kf1, s);
      sc[n16] = s;
    }

    // ---- p = exp(s/8), mask tail tile ----
    if (k0 + 64 <= L) {
#pragma unroll
      for (int n16 = 0; n16 < 4; ++n16) {
#pragma unroll
        for (int r = 0; r < 4; ++r) {
          const float p = __expf(sc[n16][r] * 0.125f);
          lsum[r] += p;
          Pw[(quad * 4 + r) * 72 + n16 * 16 + l15] = (bf16_t)p;
        }
      }
    } else {
#pragma unroll
      for (int n16 = 0; n16 < 4; ++n16) {
        const bool valid = (k0 + n16 * 16 + l15) < L;
#pragma unroll
        for (int r = 0; r < 4; ++r) {
          const float p = valid ? __expf(sc[n16][r] * 0.125f) : 0.f;
          lsum[r] += p;
          Pw[(quad * 4 + r) * 72 + n16 * 16 + l15] = (bf16_t)p;
        }
      }
    }

    // ---- O += P @ V ----
    const bf16x8 pf0 = *(const bf16x8*)(Pw + l15 * 72 + quad * 8);
    const bf16x8 pf1 = *(const bf16x8*)(Pw + l15 * 72 + 32 + quad * 8);
#pragma unroll
    for (int dt = 0; dt < 4; ++dt) {
      const int row = (dt * 16 + l15) * 32 + quad * 8;
      bf16x8 vf0 = *(const bf16x8*)(VsA + row);
      bf16x8 vf1 = *(const bf16x8*)(VsB + row);
      o[dt] = mfma_bf16(pf0, vf0, o[dt]);
      o[dt] = mfma_bf16(pf1, vf1, o[dt]);
    }
  }

  // ---- row-sum reduce, normalize, write [B,S,H*64] ----
  float inv[4];
#pragma unroll
  for (int r = 0; r < 4; ++r) {
    float t = lsum[r];
    t += __shfl_xor(t, 1, 64);
    t += __shfl_xor(t, 2, 64);
    t += __shfl_xor(t, 4, 64);
    t += __shfl_xor(t, 8, 64);
    inv[r] = 1.f / t;
  }
  const int qout = qt * 64 + wave * 16 + quad * 4;
#pragma unroll
  for (int dt = 0; dt < 4; ++dt) {
#pragma unroll
    for (int r = 0; r < 4; ++r) {
      const float v = o[dt][r] * inv[r];
      O[((size_t)(b * S_ + qout + r)) * (H_ * DH_) + h * DH_ + dt * 16 + l15] = (bf16_t)v;
    }
  }
}

// ---------------------------------------------------------------------------
extern "C" void kernel_launch(void* const* d_in, const int* in_sizes, int n_in,
                              void* d_out, int out_size, void* d_ws, size_t ws_size,
                              hipStream_t stream) {
  const float* queries = (const float*)d_in[0];
  const float* keys    = (const float*)d_in[1];
  const float* values  = (const float*)d_in[2];
  const float* Wq      = (const float*)d_in[3];
  const float* Wk      = (const float*)d_in[4];
  const float* Wv      = (const float*)d_in[5];
  const float* Wo      = (const float*)d_in[6];
  const int* valid_lens = (const int*)d_in[7];
  float* out = (float*)d_out;

  bf16_t* ws = (bf16_t*)d_ws;
  const size_t MB = 1024 * 1024;     // elements (bf16)
  bf16_t* WqT = ws + 0 * MB;         // WqT,WkT,WvT contiguous (seg<<20)
  bf16_t* WkT = ws + 1 * MB;
  bf16_t* WvT = ws + 2 * MB;
  bf16_t* WoT = ws + 3 * MB;
  bf16_t* Qc  = ws + 4 * MB;         // Qc,Kc,Vc contiguous -> fused A 24576x1024
  bf16_t* Kc  = ws + 12 * MB;
  bf16_t* Vc  = ws + 20 * MB;
  bf16_t* Qb  = ws + 28 * MB;        // Qb,Kb,Vb contiguous (seg<<23)
  bf16_t* Kb  = ws + 36 * MB;
  bf16_t* Vb  = ws + 44 * MB;
  bf16_t* VbT = ws + 52 * MB;        // [B,H,64,S] transposed V
  bf16_t* Ab  = ws + 60 * MB;        // [B,S,1024] attn out  (total 136 MB)

  (void)hipFuncSetAttribute((const void*)gemm_proj,
                            hipFuncAttributeMaxDynamicSharedMemorySize, LDS_BYTES);
  (void)hipFuncSetAttribute((const void*)gemm_out,
                            hipFuncAttributeMaxDynamicSharedMemorySize, LDS_BYTES);

  transpose4<<<dim3(16, 16, 4), 256, 0, stream>>>(Wq, Wk, Wv, Wo, WqT, WkT, WvT, WoT);

  convert_qkv<<<dim3(4096, 3), 256, 0, stream>>>(queries, keys, values, Qc, Kc, Vc);

  gemm_proj<<<dim3(768, 1, 1), 512, LDS_BYTES, stream>>>(Qc, WqT, Qb);

  transposeV<<<dim3(16, 128), 256, 0, stream>>>(Vb, VbT);

  attn64<<<dim3(16, 16, 8), 256, 0, stream>>>(Qb, Kb, VbT, valid_lens, Ab);

  gemm_out<<<dim3(256, 1, 1), 512, LDS_BYTES, stream>>>(Ab, WoT, out);
}